// Round 7
// baseline (3447.485 us; speedup 1.0000x reference)
//
#include <hip/hip_runtime.h>
#include <stdint.h>
#include <stddef.h>

// ---------------------------------------------------------------------------
// PCgraph: T=32 steps of
//   mu = tanh(x) @ w^T ; e = (x-mu)*m ; g = e @ w ;
//   x = x - 0.1*m*(e - (1-tanh(x)^2)*g)
// bf16 MFMA 16x16x32, fp32 accum. x state in d_out (fp32).
// Round 16: PERSISTENT KERNEL -- 1 dispatch for all 32 steps.
// r15 confirmed the per-dispatch-overhead model (4->2 dispatches/step =
// 1321->1032us). Endpoint: run both phases of all 32 steps in one kernel,
// with a hand-rolled grid barrier between phases.
//   - 256 blocks launched, 208 active (52 ntile x 4 mtile; surplus decode
//     slots exit before the first barrier; barrier counts NB_ACTIVE=208).
//     128KB LDS + 1024 threads => exactly 1 block/CU, grid <= 256 CUs =>
//     all active blocks co-resident => barrier cannot deadlock.
//   - barrier: sense-reversing, agent-scope acquire/release atomics
//     (__hip_atomic_*) + __threadfence -- provides the cross-XCD L2
//     coherence for e_pk/t_pk that dispatch boundaries used to provide.
//   - k-loop body is r15's verbatim (counted vmcnt(4), raw s_barrier,
//     sched_barrier(0); STAGING RULE: per-lane LDS stride EXACTLY 16B,
//     wave-uniform base -- global_load_lds HW writes base + lane*16).
//   - new fusions: x, mu0, mask held in REGISTERS across all steps (each
//     thread's epilogue element is self-owned: same tid -> same (row,col)
//     every step); e carried f32 phase1->phase2 (closer to reference than
//     bf16 readback); xbuf written once after the loop.
// ws end @ 56,623,112 < 256 MiB.
// ---------------------------------------------------------------------------

#define N_DIM 4096
#define B_DIM 256
#define T_STEPS 32
#define LR_X 0.1f
#define N0 768                      // first live column (aligned down from 784)
#define N_LIVE 3328                 // 4096 - 768 = 52*64
#define NCHL 52                     // live k-chunks (both GEMMs)
#define KG 4                        // k-groups per block
#define KITG 13                     // chunks per group (52/4)
#define NB_ACTIVE 208               // active blocks in persistent kernel

typedef unsigned short ushort_t;
using bf16x8 = __attribute__((ext_vector_type(8))) __bf16;
using f32x4  = __attribute__((ext_vector_type(4))) float;

__device__ __forceinline__ ushort_t f2bf(float f) {
    union { float f; unsigned int u; } v; v.f = f;
    unsigned int r = v.u + 0x7fffu + ((v.u >> 16) & 1u);   // RNE
    return (ushort_t)(r >> 16);
}
__device__ __forceinline__ float bf2f(ushort_t h) {
    union { unsigned int u; float f; } v; v.u = ((unsigned int)h) << 16;
    return v.f;
}

__device__ __forceinline__ void async_copy16(const ushort_t* g, ushort_t* l) {
    __builtin_amdgcn_global_load_lds(
        (__attribute__((address_space(1))) void*)(g),
        (__attribute__((address_space(3))) void*)(l),
        16, 0, 0);
}

// --- pack w -> w_pk [52 ntile][64 chunk][4096]  (B of GEMM1: rows 768..4095)
//            -> wt_pk [52 ntile][52 chunk][4096] (B of GEMM2: w^T, live range)
__global__ __launch_bounds__(256) void pack_w(const float* __restrict__ w,
                                              ushort_t* __restrict__ wpk,
                                              ushort_t* __restrict__ wtpk) {
    __shared__ float tile[64][68];
    const int tid = threadIdx.x;
    const int bid = blockIdx.x;
    int row0, col0; ushort_t* dst; bool tr;
    if (bid < 52 * 64) {
        tr   = false;
        dst  = wpk + (size_t)bid * 4096;
        row0 = N0 + (bid >> 6) * 64;      // B-row (n) block
        col0 = (bid & 63) * 64;           // k block
    } else {
        const int b2 = bid - 52 * 64;
        tr   = true;
        dst  = wtpk + (size_t)b2 * 4096;
        const int ntile = b2 / 52, chunk = b2 - ntile * 52;
        row0 = N0 + chunk * 64;           // w-row  = k block (live)
        col0 = N0 + ntile * 64;           // w-col  = n block (live)
    }
    const int rr = tid >> 2, c0 = (tid & 3) * 16;
    const float* src = w + (size_t)(row0 + rr) * N_DIM + col0 + c0;
#pragma unroll
    for (int i = 0; i < 16; i += 4)
        *(float4*)&tile[rr][c0 + i] = *(const float4*)(src + i);
    __syncthreads();
    ushort_t loc[16];
#pragma unroll
    for (int i = 0; i < 16; ++i) {
        const int p = tid * 16 + i;
        const int s = p >> 9, e = p & 511;
        const int r = ((s >> 1) << 4) | ((e >> 3) & 15);
        const int c = ((s & 1) << 5) | (((e >> 7) & 3) << 3) | (e & 7);
        loc[i] = f2bf(tr ? tile[c][r] : tile[r][c]);
    }
    *(uint4*)&dst[tid * 16]     = *(uint4*)&loc[0];
    *(uint4*)&dst[tid * 16 + 8] = *(uint4*)&loc[8];
}

// --- init: x -> d_out (row-major) and t_pk [4 mtile][64 chunk][4096] --------
__global__ __launch_bounds__(256) void pack_t_init(const float* __restrict__ xin,
                                                   float* __restrict__ xout,
                                                   ushort_t* __restrict__ tpk) {
    __shared__ float tile[64][68];
    const int tid  = threadIdx.x;
    const int bid  = blockIdx.x;          // mtile*64 + chunk
    const int row0 = (bid >> 6) * 64;
    const int col0 = (bid & 63) * 64;
    const int rr = tid >> 2, c0 = (tid & 3) * 16;
    const size_t sidx = (size_t)(row0 + rr) * N_DIM + col0 + c0;
#pragma unroll
    for (int i = 0; i < 16; i += 4) {
        float4 v = *(const float4*)(xin + sidx + i);
        *(float4*)(xout + sidx + i) = v;
        tile[rr][c0 + i + 0] = tanhf(v.x);
        tile[rr][c0 + i + 1] = tanhf(v.y);
        tile[rr][c0 + i + 2] = tanhf(v.z);
        tile[rr][c0 + i + 3] = tanhf(v.w);
    }
    __syncthreads();
    ushort_t loc[16];
    ushort_t* dst = tpk + (size_t)bid * 4096;
#pragma unroll
    for (int i = 0; i < 16; ++i) {
        const int p = tid * 16 + i;
        const int s = p >> 9, e = p & 511;
        const int r = ((s >> 1) << 4) | ((e >> 3) & 15);
        const int c = ((s & 1) << 5) | (((e >> 7) & 3) << 3) | (e & 7);
        loc[i] = f2bf(tile[r][c]);
    }
    *(uint4*)&dst[tid * 16]     = *(uint4*)&loc[0];
    *(uint4*)&dst[tid * 16 + 8] = *(uint4*)&loc[8];
}

// --- one-time: mu0 = tanh(x_sensory) @ w_sensory^T  (k = chunks 0..11) ------
__global__ __launch_bounds__(256) void gemm_mu0(const ushort_t* __restrict__ Apk,
                                                const ushort_t* __restrict__ Bpk,
                                                float* __restrict__ mu0) {
    __shared__ __align__(16) ushort_t As[2][4096];
    __shared__ __align__(16) ushort_t Bs[2][4096];
    const int tid  = threadIdx.x;
    const int lane = tid & 63;
    const int wid  = tid >> 6;
    const int wave_m = wid >> 1, wave_n = wid & 1;
    const int ntile = blockIdx.x, mtile = blockIdx.y;

    const ushort_t* Ab = Apk + (size_t)mtile * 64 * 4096;
    const ushort_t* Bb = Bpk + (size_t)ntile * 64 * 4096;

    auto stage = [&](int buf, int kt) {
#pragma unroll
        for (int u = 0; u < 2; ++u) {
            const int off = (wid * 2 + u) * 512 + lane * 8;
            async_copy16(Ab + (size_t)kt * 4096 + off, &As[buf][off]);
            async_copy16(Bb + (size_t)kt * 4096 + off, &Bs[buf][off]);
        }
    };
    f32x4 acc[2][2] = {};
    auto compute = [&](int buf) {
#pragma unroll
        for (int ks = 0; ks < 2; ++ks) {
            bf16x8 a[2], b[2];
#pragma unroll
            for (int i = 0; i < 2; ++i) {
                const int asub = (wave_m * 2 + i) * 2 + ks;
                const int bsub = (wave_n * 2 + i) * 2 + ks;
                a[i] = *(const bf16x8*)(&As[buf][asub * 512 + lane * 8]);
                b[i] = *(const bf16x8*)(&Bs[buf][bsub * 512 + lane * 8]);
            }
#pragma unroll
            for (int i = 0; i < 2; ++i)
#pragma unroll
                for (int j = 0; j < 2; ++j)
                    acc[i][j] = __builtin_amdgcn_mfma_f32_16x16x32_bf16(
                        a[i], b[j], acc[i][j], 0, 0, 0);
        }
    };
    stage(0, 0);
    __syncthreads();
    for (int kt = 0; kt < 12; ++kt) {          // sensory chunks 0..11
        if (kt + 1 < 12) stage((kt + 1) & 1, kt + 1);
        compute(kt & 1);
        __syncthreads();
    }
    const int l15 = lane & 15, quad = lane >> 4;
#pragma unroll
    for (int j = 0; j < 2; ++j) {
        const int nl = ntile * 64 + wave_n * 32 + j * 16 + l15;
#pragma unroll
        for (int i = 0; i < 2; ++i)
#pragma unroll
            for (int r = 0; r < 4; ++r) {
                const int m = mtile * 64 + wave_m * 32 + i * 16 + quad * 4 + r;
                mu0[(size_t)m * N_LIVE + nl] = acc[i][j][r];
            }
    }
}

// --- barrier init (ws is poison-filled between runs; must zero each launch) -
__global__ void bar_init(unsigned* bar) { bar[0] = 0u; bar[1] = 0u; }

// --- grid barrier: sense-reversing, agent-scope acq/rel ---------------------
__device__ __forceinline__ void grid_bar(unsigned* bar) {
    __syncthreads();
    if (threadIdx.x == 0) {
        __threadfence();   // belt-and-suspenders device-scope release
        unsigned g = __hip_atomic_load(&bar[1], __ATOMIC_RELAXED,
                                       __HIP_MEMORY_SCOPE_AGENT);
        unsigned v = __hip_atomic_fetch_add(&bar[0], 1u, __ATOMIC_ACQ_REL,
                                            __HIP_MEMORY_SCOPE_AGENT);
        if (v == NB_ACTIVE - 1) {
            __hip_atomic_store(&bar[0], 0u, __ATOMIC_RELAXED,
                               __HIP_MEMORY_SCOPE_AGENT);
            __hip_atomic_fetch_add(&bar[1], 1u, __ATOMIC_RELEASE,
                                   __HIP_MEMORY_SCOPE_AGENT);
        } else {
            while (__hip_atomic_load(&bar[1], __ATOMIC_ACQUIRE,
                                     __HIP_MEMORY_SCOPE_AGENT) == g)
                __builtin_amdgcn_s_sleep(2);
        }
        __threadfence();   // acquire side: invalidate stale cached lines
    }
    __syncthreads();
}

// --- persistent kernel: all 32 steps, 2 phases/step, 2 grid barriers/step ---
// Block = (ntile, mtile) fixed for the whole run; 1024 threads = 4 k-groups
// x 4 waves. Per phase: r15's counted-vmcnt k-loop over the group's 13
// chunks, f32 cross-group LDS reduction, fused cvt epilogue. x/mu0/mask in
// registers for all 32 steps (thread's epilogue element is self-owned);
// e carried f32 from phase 1 to phase 2; xbuf written once at the end.
__global__ __launch_bounds__(1024) void pc_persist(
    const ushort_t* __restrict__ w_pk,
    const ushort_t* __restrict__ wt_pk,
    ushort_t* __restrict__ t_pk,
    ushort_t* __restrict__ e_pk,
    float* __restrict__ xbuf,
    const float* __restrict__ mu0,
    const int* __restrict__ mask,
    unsigned* __restrict__ bar) {
    __shared__ __align__(16) ushort_t smem[65536];   // 128 KB
    ushort_t* As = smem;                              // [g*2+buf][4096]
    ushort_t* Bs = smem + 32768;

    const int bid = blockIdx.x;
    const int xcd = bid & 7;
    const int i   = bid >> 3;                 // 0..31
    const int nloc = (xcd < 4) ? 7 : 6;
    if (i >= nloc * 4) return;                // surplus: exit before barrier 0
    const int n0    = (xcd < 4) ? xcd * 7 : 28 + (xcd - 4) * 6;
    const int ntile = n0 + (i >> 2);          // 0..51
    const int mtile = i & 3;                  // 0..3

    const int tid  = threadIdx.x;
    const int lane = tid & 63;
    const int g    = tid >> 8;                // k-group 0..3
    const int gtid = tid & 255;
    const int gw   = (tid >> 6) & 3;          // wave within group
    const int wave_m = gw >> 1, wave_n = gw & 1;
    const int l15 = lane & 15, quad = lane >> 4;

    ushort_t* Asg = As + g * 2 * 4096;
    ushort_t* Bsg = Bs + g * 2 * 4096;

    // epilogue decode: thread owns 4 consecutive packed positions
    const int p4 = tid * 4;
    const int s  = p4 >> 9, e9 = p4 & 511;
    const int rr = ((s >> 1) << 4) | ((e9 >> 3) & 15);
    const int cc = ((s & 1) << 5) | (((e9 >> 7) & 3) << 3) | (e9 & 7);
    const int grow = mtile * 64 + rr;         // batch row
    const int gcl  = ntile * 64 + cc;         // live col
    const size_t xi = (size_t)grow * N_DIM + N0 + gcl;

    float* red = (float*)smem;                // 4 x 64*68 f32 (69.6 KB)
    const int RP = 64 * 68;

    // ---- persistent per-thread state ----
    float4 xv = *(const float4*)&xbuf[xi];
    const int4   mk = *(const int4*)&mask[N0 + gcl];
    const float4 m0 = *(const float4*)&mu0[(size_t)grow * N_LIVE + gcl];
    float em[4];                              // e (f32), phase1 -> phase2

    // ---- k-loop (r15 verbatim; STAGING RULE: lane stride 16B) ----
    auto run_panel = [&](const ushort_t* Ab, const ushort_t* Bb,
                         f32x4 (&acc)[2][2]) {
        auto stage = [&](int buf, int kt) {
            const ushort_t* Ac = Ab + (size_t)kt * 4096;
            const ushort_t* Bc = Bb + (size_t)kt * 4096;
#pragma unroll
            for (int u = 0; u < 2; ++u) {
                const int off = (u * 256 + gtid) * 8;
                async_copy16(Ac + off, &Asg[buf * 4096 + off]);
                async_copy16(Bc + off, &Bsg[buf * 4096 + off]);
            }
        };
        auto compute = [&](int buf) {
#pragma unroll
            for (int ks = 0; ks < 2; ++ks) {
                bf16x8 a[2], b[2];
#pragma unroll
                for (int i2 = 0; i2 < 2; ++i2) {
                    const int asub = (wave_m * 2 + i2) * 2 + ks;
                    const int bsub = (wave_n * 2 + i2) * 2 + ks;
                    a[i2] = *(const bf16x8*)(&Asg[buf * 4096 + asub * 512 + lane * 8]);
                    b[i2] = *(const bf16x8*)(&Bsg[buf * 4096 + bsub * 512 + lane * 8]);
                }
#pragma unroll
                for (int i2 = 0; i2 < 2; ++i2)
#pragma unroll
                    for (int j = 0; j < 2; ++j)
                        acc[i2][j] = __builtin_amdgcn_mfma_f32_16x16x32_bf16(
                            a[i2], b[j], acc[i2][j], 0, 0, 0);
            }
        };
        stage(0, 0);
        for (int kt = 0; kt < KITG; ++kt) {
            if (kt + 1 < KITG) {
                stage((kt + 1) & 1, kt + 1);
                asm volatile("s_waitcnt vmcnt(4)" ::: "memory");
            } else {
                asm volatile("s_waitcnt vmcnt(0)" ::: "memory");
            }
            __builtin_amdgcn_s_barrier();
            __builtin_amdgcn_sched_barrier(0);
            compute(kt & 1);
            __builtin_amdgcn_s_barrier();
        }
    };

    // ---- cross-group f32 reduction through LDS ----
    auto reduce_sum = [&](f32x4 (&acc)[2][2]) -> float4 {
        __syncthreads();
#pragma unroll
        for (int j = 0; j < 2; ++j) {
            const int col = wave_n * 32 + j * 16 + l15;
#pragma unroll
            for (int i2 = 0; i2 < 2; ++i2)
#pragma unroll
                for (int r = 0; r < 4; ++r) {
                    const int row = wave_m * 32 + i2 * 16 + quad * 4 + r;
                    red[g * RP + row * 68 + col] = acc[i2][j][r];
                }
        }
        __syncthreads();
        float4 sv = *(const float4*)&red[0 * RP + rr * 68 + cc];
#pragma unroll
        for (int gg = 1; gg < KG; ++gg) {
            float4 v = *(const float4*)&red[gg * RP + rr * 68 + cc];
            sv.x += v.x; sv.y += v.y; sv.z += v.z; sv.w += v.w;
        }
        return sv;
    };

    const ushort_t* Ab1 = t_pk + ((size_t)(mtile * 64 + 12 + g * KITG)) * 4096;
    const ushort_t* Bb1 = w_pk + ((size_t)(ntile * 64 + 12 + g * KITG)) * 4096;
    const ushort_t* Ab2 = e_pk + ((size_t)(mtile * NCHL + g * KITG)) * 4096;
    const ushort_t* Bb2 = wt_pk + ((size_t)(ntile * NCHL + g * KITG)) * 4096;
    ushort_t* eout = e_pk + ((size_t)(mtile * NCHL + ntile)) * 4096 + p4;
    ushort_t* tout = t_pk + ((size_t)(mtile * 64 + 12 + ntile)) * 4096 + p4;

    for (int t = 0; t < T_STEPS; ++t) {
        // ---- phase 1: mu = mu0 + tanh(x)@w^T ; e = (x-mu)*m -> e_pk --------
        {
            f32x4 acc[2][2] = {};
            run_panel(Ab1, Bb1, acc);
            float4 sv = reduce_sum(acc);
            em[0] = (xv.x - (m0.x + sv.x)) * (float)mk.x;
            em[1] = (xv.y - (m0.y + sv.y)) * (float)mk.y;
            em[2] = (xv.z - (m0.z + sv.z)) * (float)mk.z;
            em[3] = (xv.w - (m0.w + sv.w)) * (float)mk.w;
            ushort_t ev[4] = { f2bf(em[0]), f2bf(em[1]), f2bf(em[2]), f2bf(em[3]) };
            *(uint2*)eout = *(uint2*)&ev[0];
        }
        grid_bar(bar);
        // ---- phase 2: g = e@w ; x -= 0.1*m*(e - (1-tanh^2)*g) ; t_pk -------
        {
            f32x4 acc[2][2] = {};
            run_panel(Ab2, Bb2, acc);
            float4 sv = reduce_sum(acc);
            float* xp = &xv.x;
            const float* svp = &sv.x;
            const int* mkp = &mk.x;
            ushort_t tv[4];
#pragma unroll
            for (int q = 0; q < 4; ++q) {
                const float x  = xp[q];
                const float th = tanhf(x);
                xp[q] = x - LR_X * (float)mkp[q]
                            * (em[q] - (1.0f - th * th) * svp[q]);
                tv[q] = f2bf(tanhf(xp[q]));
            }
            *(uint2*)tout = *(uint2*)&tv[0];
        }
        grid_bar(bar);
    }
    *(float4*)&xbuf[xi] = xv;
}

extern "C" void kernel_launch(void* const* d_in, const int* in_sizes, int n_in,
                              void* d_out, int out_size, void* d_ws, size_t ws_size,
                              hipStream_t stream) {
    const float* x_in  = (const float*)d_in[0];
    const float* w_in  = (const float*)d_in[1];
    const int*   mask  = (const int*)d_in[2];
    float*       xbuf  = (float*)d_out;          // state lives in d_out

    uint8_t* ws = (uint8_t*)d_ws;
    // ws layout (end @ 56,623,112 bytes; ws_size = 256 MiB per fillBuffer):
    ushort_t* w_pk  = (ushort_t*)(ws);                   // 52*64*4096*2 = 27,262,976
    ushort_t* wt_pk = (ushort_t*)(ws + 27262976);        // 52*52*4096*2 = 22,151,168
    ushort_t* t_pk  = (ushort_t*)(ws + 49414144);        //  4*64*4096*2 =  2,097,152
    ushort_t* e_pk  = (ushort_t*)(ws + 51511296);        //  4*52*4096*2 =  1,703,936
    float*    mu0   = (float*)(ws + 53215232);           //  256*3328*4  =  3,407,872
    unsigned* bar   = (unsigned*)(ws + 56623104);        //  2*4 = 8

    pack_w<<<dim3(52 * 64 + 52 * 52), 256, 0, stream>>>(w_in, w_pk, wt_pk);
    pack_t_init<<<dim3(4 * 64), 256, 0, stream>>>(x_in, xbuf, t_pk);
    gemm_mu0<<<dim3(52, 4), 256, 0, stream>>>(t_pk, w_pk, mu0);
    bar_init<<<1, 1, 0, stream>>>(bar);

    pc_persist<<<256, 1024, 0, stream>>>(
        w_pk, wt_pk, t_pk, e_pk, xbuf, mu0, mask, bar);
}

// Round 9
// 1359.212 us; speedup vs baseline: 2.5364x; 2.5364x over previous
//
#include <hip/hip_runtime.h>
#include <stdint.h>
#include <stddef.h>

// ---------------------------------------------------------------------------
// PCgraph: T=32 steps of
//   mu = tanh(x) @ w^T ; e = (x-mu)*m ; g = e @ w ;
//   x = x - 0.1*m*(e - (1-tanh(x)^2)*g)
// bf16 MFMA 16x16x32, fp32 accum. x state in d_out (fp32).
// Round 18 == Round 17 resubmitted (round-8 bench was an infra failure:
// "MI355X container failed twice"; no counters. Kernel re-audited: no
// divergent barriers, vmcnt counting correct, no LDS hazards).
// DUAL-PATH STAGING on the r15 skeleton (r16 persistent reverted: its
// grid-barrier fences invalidated L2 every step -> 3.2GB HBM refetch,
// 3447us). r15 budget: phase = 832KB/block staged at a fill rate pinned at
// ~18 B/cy/CU across r9/r12/r15 -- ALL staging went through the LDS-DMA
// path (global_load_lds). m97 showed 44 B/cy/CU is possible. Hypothesis:
// per-CU LDS-DMA engine saturates ~20B/cy while the normal vector-load
// return path sits idle. Fix: stage A via global_load_lds (unchanged,
// STAGING RULE: 16B lane stride, wave-uniform base) and B via
// global_load->regs->ds_write_b128 (T14 split: loads issued one tile early;
// ds_write + lgkmcnt(0) just before the consume barrier). Per iter:
//   dma A(kt+1); ld B(kt+1)->n; vmcnt(4)  [drains tile-kt's 4 older ops]
//   ds_write B(kt) from c; lgkmcnt(0); s_barrier; sched_barrier;
//   compute(kt); s_barrier; c=n
// Reg sets hand-named (no dynamic indexing -> no scratch). Everything else
// (fused 2-dispatch structure, f32 reduction, epilogues, mu0, XCD pinning)
// is r15 verbatim. ws end @ 56,623,104 < 256 MiB.
// ---------------------------------------------------------------------------

#define N_DIM 4096
#define B_DIM 256
#define T_STEPS 32
#define LR_X 0.1f
#define N0 768                      // first live column (aligned down from 784)
#define N_LIVE 3328                 // 4096 - 768 = 52*64
#define NCHL 52                     // live k-chunks (both GEMMs)
#define KG 4                        // k-groups per block
#define KITG 13                     // chunks per group (52/4)

typedef unsigned short ushort_t;
using bf16x8 = __attribute__((ext_vector_type(8))) __bf16;
using f32x4  = __attribute__((ext_vector_type(4))) float;

__device__ __forceinline__ ushort_t f2bf(float f) {
    union { float f; unsigned int u; } v; v.f = f;
    unsigned int r = v.u + 0x7fffu + ((v.u >> 16) & 1u);   // RNE
    return (ushort_t)(r >> 16);
}
__device__ __forceinline__ float bf2f(ushort_t h) {
    union { unsigned int u; float f; } v; v.u = ((unsigned int)h) << 16;
    return v.f;
}

__device__ __forceinline__ void async_copy16(const ushort_t* g, ushort_t* l) {
    __builtin_amdgcn_global_load_lds(
        (__attribute__((address_space(1))) void*)(g),
        (__attribute__((address_space(3))) void*)(l),
        16, 0, 0);
}

// --- pack w -> w_pk [52 ntile][64 chunk][4096]  (B of GEMM1: rows 768..4095)
//            -> wt_pk [52 ntile][52 chunk][4096] (B of GEMM2: w^T, live range)
__global__ __launch_bounds__(256) void pack_w(const float* __restrict__ w,
                                              ushort_t* __restrict__ wpk,
                                              ushort_t* __restrict__ wtpk) {
    __shared__ float tile[64][68];
    const int tid = threadIdx.x;
    const int bid = blockIdx.x;
    int row0, col0; ushort_t* dst; bool tr;
    if (bid < 52 * 64) {
        tr   = false;
        dst  = wpk + (size_t)bid * 4096;
        row0 = N0 + (bid >> 6) * 64;      // B-row (n) block
        col0 = (bid & 63) * 64;           // k block
    } else {
        const int b2 = bid - 52 * 64;
        tr   = true;
        dst  = wtpk + (size_t)b2 * 4096;
        const int ntile = b2 / 52, chunk = b2 - ntile * 52;
        row0 = N0 + chunk * 64;           // w-row  = k block (live)
        col0 = N0 + ntile * 64;           // w-col  = n block (live)
    }
    const int rr = tid >> 2, c0 = (tid & 3) * 16;
    const float* src = w + (size_t)(row0 + rr) * N_DIM + col0 + c0;
#pragma unroll
    for (int i = 0; i < 16; i += 4)
        *(float4*)&tile[rr][c0 + i] = *(const float4*)(src + i);
    __syncthreads();
    ushort_t loc[16];
#pragma unroll
    for (int i = 0; i < 16; ++i) {
        const int p = tid * 16 + i;
        const int s = p >> 9, e = p & 511;
        const int r = ((s >> 1) << 4) | ((e >> 3) & 15);
        const int c = ((s & 1) << 5) | (((e >> 7) & 3) << 3) | (e & 7);
        loc[i] = f2bf(tr ? tile[c][r] : tile[r][c]);
    }
    *(uint4*)&dst[tid * 16]     = *(uint4*)&loc[0];
    *(uint4*)&dst[tid * 16 + 8] = *(uint4*)&loc[8];
}

// --- init: x -> d_out (row-major) and t_pk [4 mtile][64 chunk][4096] --------
__global__ __launch_bounds__(256) void pack_t_init(const float* __restrict__ xin,
                                                   float* __restrict__ xout,
                                                   ushort_t* __restrict__ tpk) {
    __shared__ float tile[64][68];
    const int tid  = threadIdx.x;
    const int bid  = blockIdx.x;          // mtile*64 + chunk
    const int row0 = (bid >> 6) * 64;
    const int col0 = (bid & 63) * 64;
    const int rr = tid >> 2, c0 = (tid & 3) * 16;
    const size_t sidx = (size_t)(row0 + rr) * N_DIM + col0 + c0;
#pragma unroll
    for (int i = 0; i < 16; i += 4) {
        float4 v = *(const float4*)(xin + sidx + i);
        *(float4*)(xout + sidx + i) = v;
        tile[rr][c0 + i + 0] = tanhf(v.x);
        tile[rr][c0 + i + 1] = tanhf(v.y);
        tile[rr][c0 + i + 2] = tanhf(v.z);
        tile[rr][c0 + i + 3] = tanhf(v.w);
    }
    __syncthreads();
    ushort_t loc[16];
    ushort_t* dst = tpk + (size_t)bid * 4096;
#pragma unroll
    for (int i = 0; i < 16; ++i) {
        const int p = tid * 16 + i;
        const int s = p >> 9, e = p & 511;
        const int r = ((s >> 1) << 4) | ((e >> 3) & 15);
        const int c = ((s & 1) << 5) | (((e >> 7) & 3) << 3) | (e & 7);
        loc[i] = f2bf(tile[r][c]);
    }
    *(uint4*)&dst[tid * 16]     = *(uint4*)&loc[0];
    *(uint4*)&dst[tid * 16 + 8] = *(uint4*)&loc[8];
}

// --- one-time: mu0 = tanh(x_sensory) @ w_sensory^T  (k = chunks 0..11) ------
__global__ __launch_bounds__(256) void gemm_mu0(const ushort_t* __restrict__ Apk,
                                                const ushort_t* __restrict__ Bpk,
                                                float* __restrict__ mu0) {
    __shared__ __align__(16) ushort_t As[2][4096];
    __shared__ __align__(16) ushort_t Bs[2][4096];
    const int tid  = threadIdx.x;
    const int lane = tid & 63;
    const int wid  = tid >> 6;
    const int wave_m = wid >> 1, wave_n = wid & 1;
    const int ntile = blockIdx.x, mtile = blockIdx.y;

    const ushort_t* Ab = Apk + (size_t)mtile * 64 * 4096;
    const ushort_t* Bb = Bpk + (size_t)ntile * 64 * 4096;

    auto stage = [&](int buf, int kt) {
#pragma unroll
        for (int u = 0; u < 2; ++u) {
            const int off = (wid * 2 + u) * 512 + lane * 8;
            async_copy16(Ab + (size_t)kt * 4096 + off, &As[buf][off]);
            async_copy16(Bb + (size_t)kt * 4096 + off, &Bs[buf][off]);
        }
    };
    f32x4 acc[2][2] = {};
    auto compute = [&](int buf) {
#pragma unroll
        for (int ks = 0; ks < 2; ++ks) {
            bf16x8 a[2], b[2];
#pragma unroll
            for (int i = 0; i < 2; ++i) {
                const int asub = (wave_m * 2 + i) * 2 + ks;
                const int bsub = (wave_n * 2 + i) * 2 + ks;
                a[i] = *(const bf16x8*)(&As[buf][asub * 512 + lane * 8]);
                b[i] = *(const bf16x8*)(&Bs[buf][bsub * 512 + lane * 8]);
            }
#pragma unroll
            for (int i = 0; i < 2; ++i)
#pragma unroll
                for (int j = 0; j < 2; ++j)
                    acc[i][j] = __builtin_amdgcn_mfma_f32_16x16x32_bf16(
                        a[i], b[j], acc[i][j], 0, 0, 0);
        }
    };
    stage(0, 0);
    __syncthreads();
    for (int kt = 0; kt < 12; ++kt) {          // sensory chunks 0..11
        if (kt + 1 < 12) stage((kt + 1) & 1, kt + 1);
        compute(kt & 1);
        __syncthreads();
    }
    const int l15 = lane & 15, quad = lane >> 4;
#pragma unroll
    for (int j = 0; j < 2; ++j) {
        const int nl = ntile * 64 + wave_n * 32 + j * 16 + l15;
#pragma unroll
        for (int i = 0; i < 2; ++i)
#pragma unroll
            for (int r = 0; r < 4; ++r) {
                const int m = mtile * 64 + wave_m * 32 + i * 16 + quad * 4 + r;
                mu0[(size_t)m * N_LIVE + nl] = acc[i][j][r];
            }
    }
}

// --- fused full-K GEMM + cvt epilogue, dual-path staging --------------------
// Apk: [4 mtile][SA chunk][4096], Bpk: [52 ntile][SB chunk][4096].
// 208 active blocks (52 ntile x 4 mtile), 1024 threads = 4 k-groups x 4
// waves. A staged via global_load_lds (LDS-DMA path); B staged via
// global_load -> regs -> ds_write_b128 (vector-load path). The two HW paths
// run in parallel -> fill rate should ~2x if the DMA engine was the wall.
// Loop (per k-iter):
//   dma A(kt+1); ld B(kt+1)->n; vmcnt(4)   <- tile-kt's 4 older ops drained
//   ds_write B(kt) from c; lgkmcnt(0); s_barrier; sched_barrier(0)
//   compute(kt); s_barrier; c = n
// STAGING RULE (A only): per-lane LDS stride EXACTLY 16B, wave-uniform base.
// Epilogue identical to r15 (f32 cross-group reduce, fused cvt, packed
// chunk outputs). XCD-pinned ntiles.
template <int SA, int SB, int CO, int PHASE>
__global__ __launch_bounds__(1024) void gemm_fused(
    const ushort_t* __restrict__ Apk,
    const ushort_t* __restrict__ Bpk,
    float* __restrict__ xbuf,
    const float* __restrict__ mu0,
    const int* __restrict__ mask,
    ushort_t* __restrict__ epk,
    ushort_t* __restrict__ tpk) {
    __shared__ __align__(16) ushort_t smem[65536];   // 128 KB
    ushort_t* As = smem;                              // [g*2+buf][4096]
    ushort_t* Bs = smem + 32768;                      // [g*2+buf][4096]

    const int bid = blockIdx.x;
    const int xcd = bid & 7;
    const int i   = bid >> 3;                 // 0..31
    const int nloc = (xcd < 4) ? 7 : 6;
    if (i >= nloc * 4) return;
    const int n0    = (xcd < 4) ? xcd * 7 : 28 + (xcd - 4) * 6;
    const int ntile = n0 + (i >> 2);          // 0..51
    const int mtile = i & 3;                  // 0..3

    const int tid  = threadIdx.x;
    const int lane = tid & 63;
    const int g    = tid >> 8;                // k-group 0..3
    const int gtid = tid & 255;
    const int gw   = (tid >> 6) & 3;          // wave within group
    const int wave_m = gw >> 1, wave_n = gw & 1;

    const ushort_t* Ab = Apk + ((size_t)mtile * SA + CO + g * KITG) * 4096;
    const ushort_t* Bb = Bpk + ((size_t)ntile * SB + CO + g * KITG) * 4096;

    ushort_t* Asg = As + g * 2 * 4096;
    ushort_t* Bsg = Bs + g * 2 * 4096;

    // A: LDS-DMA (lane stride 16B, wave-uniform base per u)
    auto stage_dma = [&](int buf, int kt) {
        const ushort_t* Ac = Ab + (size_t)kt * 4096;
#pragma unroll
        for (int u = 0; u < 2; ++u) {
            const int off = (u * 256 + gtid) * 8;
            async_copy16(Ac + off, &Asg[buf * 4096 + off]);
        }
    };
    // B: vector loads into regs (issued one tile early)
    auto stage_ld = [&](int kt, uint4& r0, uint4& r1) {
        const ushort_t* Bc = Bb + (size_t)kt * 4096;
        r0 = *(const uint4*)(Bc + gtid * 8);
        r1 = *(const uint4*)(Bc + (256 + gtid) * 8);
    };
    auto stage_wr = [&](int buf, const uint4& r0, const uint4& r1) {
        *(uint4*)&Bsg[buf * 4096 + gtid * 8]         = r0;
        *(uint4*)&Bsg[buf * 4096 + (256 + gtid) * 8] = r1;
    };

    f32x4 acc[2][2] = {};

    auto compute = [&](int buf) {
#pragma unroll
        for (int ks = 0; ks < 2; ++ks) {
            bf16x8 a[2], b[2];
#pragma unroll
            for (int i2 = 0; i2 < 2; ++i2) {
                const int asub = (wave_m * 2 + i2) * 2 + ks;
                const int bsub = (wave_n * 2 + i2) * 2 + ks;
                a[i2] = *(const bf16x8*)(&Asg[buf * 4096 + asub * 512 + lane * 8]);
                b[i2] = *(const bf16x8*)(&Bsg[buf * 4096 + bsub * 512 + lane * 8]);
            }
#pragma unroll
            for (int i2 = 0; i2 < 2; ++i2)
#pragma unroll
                for (int j = 0; j < 2; ++j)
                    acc[i2][j] = __builtin_amdgcn_mfma_f32_16x16x32_bf16(
                        a[i2], b[j], acc[i2][j], 0, 0, 0);
        }
    };

    // ---- k-loop: dual-path, counted vmcnt, raw barriers ----
    uint4 c0, c1, n0r, n1r;
    stage_dma(0, 0);
    stage_ld(0, c0, c1);
    for (int kt = 0; kt < KITG; ++kt) {
        if (kt + 1 < KITG) {
            stage_dma((kt + 1) & 1, kt + 1);
            stage_ld(kt + 1, n0r, n1r);
            asm volatile("s_waitcnt vmcnt(4)" ::: "memory");
        } else {
            asm volatile("s_waitcnt vmcnt(0)" ::: "memory");
        }
        stage_wr(kt & 1, c0, c1);
        asm volatile("s_waitcnt lgkmcnt(0)" ::: "memory");
        __builtin_amdgcn_s_barrier();
        __builtin_amdgcn_sched_barrier(0);
        compute(kt & 1);
        __builtin_amdgcn_s_barrier();
        c0 = n0r; c1 = n1r;
    }
    __syncthreads();                     // repurpose LDS for reduction

    // ---- cross-group f32 reduction: red[g] = 64x68-padded f32 tile ---------
    float* red = (float*)smem;           // 4 x 64*68*4B = 69.6 KB
    const int RP = 64 * 68;
    {
        const int l15 = lane & 15, quad = lane >> 4;
#pragma unroll
        for (int j = 0; j < 2; ++j) {
            const int col = wave_n * 32 + j * 16 + l15;
#pragma unroll
            for (int i2 = 0; i2 < 2; ++i2)
#pragma unroll
                for (int r = 0; r < 4; ++r) {
                    const int row = wave_m * 32 + i2 * 16 + quad * 4 + r;
                    red[g * RP + row * 68 + col] = acc[i2][j][r];
                }
        }
    }
    __syncthreads();

    // ---- fused epilogue: thread owns 4 consecutive packed positions --------
    const int p4 = tid * 4;
    const int s  = p4 >> 9, e9 = p4 & 511;
    const int r  = ((s >> 1) << 4) | ((e9 >> 3) & 15);
    const int c  = ((s & 1) << 5) | (((e9 >> 7) & 3) << 3) | (e9 & 7);

    float4 sv = *(const float4*)&red[0 * RP + r * 68 + c];
#pragma unroll
    for (int gg = 1; gg < KG; ++gg) {
        float4 v = *(const float4*)&red[gg * RP + r * 68 + c];
        sv.x += v.x; sv.y += v.y; sv.z += v.z; sv.w += v.w;
    }

    const int grow = mtile * 64 + r;          // batch row
    const int gcl  = ntile * 64 + c;          // live col
    const size_t xi = (size_t)grow * N_DIM + N0 + gcl;
    float4 xv = *(const float4*)&xbuf[xi];
    int4   mk = *(const int4*)&mask[N0 + gcl];

    if (PHASE == 1) {
        float4 m0 = *(const float4*)&mu0[(size_t)grow * N_LIVE + gcl];
        ushort_t ev[4];
        ev[0] = f2bf((xv.x - (m0.x + sv.x)) * (float)mk.x);
        ev[1] = f2bf((xv.y - (m0.y + sv.y)) * (float)mk.y);
        ev[2] = f2bf((xv.z - (m0.z + sv.z)) * (float)mk.z);
        ev[3] = f2bf((xv.w - (m0.w + sv.w)) * (float)mk.w);
        *(uint2*)&epk[((size_t)(mtile * NCHL + ntile)) * 4096 + p4]
            = *(uint2*)&ev[0];
    } else {
        // e read back through Apk (Apk IS e_pk in phase 2; same packed chunk)
        const ushort_t* ech = Apk + ((size_t)(mtile * SA + ntile)) * 4096;
        ushort_t ein[4];
        *(uint2*)&ein[0] = *(const uint2*)&ech[p4];
        float xn[4]; ushort_t tv[4];
        const float* svp = &sv.x;
        const int*   mkp = &mk.x;
        const float* xvp = &xv.x;
#pragma unroll
        for (int q = 0; q < 4; ++q) {
            const float x  = xvp[q];
            const float th = tanhf(x);
            const float ee = bf2f(ein[q]);
            xn[q] = x - LR_X * (float)mkp[q] * (ee - (1.0f - th * th) * svp[q]);
            tv[q] = f2bf(tanhf(xn[q]));
        }
        *(float4*)&xbuf[xi] = make_float4(xn[0], xn[1], xn[2], xn[3]);
        *(uint2*)&tpk[((size_t)(mtile * 64 + 12 + ntile)) * 4096 + p4]
            = *(uint2*)&tv[0];
    }
}

extern "C" void kernel_launch(void* const* d_in, const int* in_sizes, int n_in,
                              void* d_out, int out_size, void* d_ws, size_t ws_size,
                              hipStream_t stream) {
    const float* x_in  = (const float*)d_in[0];
    const float* w_in  = (const float*)d_in[1];
    const int*   mask  = (const int*)d_in[2];
    float*       xbuf  = (float*)d_out;          // state lives in d_out

    uint8_t* ws = (uint8_t*)d_ws;
    // ws layout (end @ 56,623,104 bytes; ws_size = 256 MiB per fillBuffer):
    ushort_t* w_pk  = (ushort_t*)(ws);                   // 52*64*4096*2 = 27,262,976
    ushort_t* wt_pk = (ushort_t*)(ws + 27262976);        // 52*52*4096*2 = 22,151,168
    ushort_t* t_pk  = (ushort_t*)(ws + 49414144);        //  4*64*4096*2 =  2,097,152
    ushort_t* e_pk  = (ushort_t*)(ws + 51511296);        //  4*52*4096*2 =  1,703,936
    float*    mu0   = (float*)(ws + 53215232);           //  256*3328*4  =  3,407,872

    pack_w<<<dim3(52 * 64 + 52 * 52), 256, 0, stream>>>(w_in, w_pk, wt_pk);
    pack_t_init<<<dim3(4 * 64), 256, 0, stream>>>(x_in, xbuf, t_pk);
    gemm_mu0<<<dim3(52, 4), 256, 0, stream>>>(t_pk, w_pk, mu0);

    for (int t = 0; t < T_STEPS; ++t) {
        // GEMM1+cvt1: e = (x - mu)*mask -> e_pk   (A = t_pk, B = w_pk)
        gemm_fused<64, 64, 12, 1><<<256, 1024, 0, stream>>>(
            t_pk, w_pk, xbuf, mu0, mask, e_pk, t_pk);
        // GEMM2+cvt2: x update -> xbuf, tanh -> t_pk (A = e_pk, B = wt_pk)
        gemm_fused<52, 52, 0, 2><<<256, 1024, 0, stream>>>(
            e_pk, wt_pk, xbuf, mu0, mask, e_pk, t_pk);
    }
}

// Round 10
// 1207.116 us; speedup vs baseline: 2.8560x; 1.1260x over previous
//
#include <hip/hip_runtime.h>
#include <stdint.h>
#include <stddef.h>

// ---------------------------------------------------------------------------
// PCgraph: T=32 steps of
//   mu = tanh(x) @ w^T ; e = (x-mu)*m ; g = e @ w ;
//   x = x - 0.1*m*(e - (1-tanh(x)^2)*g)
// bf16 MFMA 16x16x32, fp32 accum. x state in d_out (fp32).
// Round 19: PER-GROUP LDS-ATOMIC BARRIERS on the r15 skeleton (r17/18
// dual-path reverted: -32%, the serialized ds_write+lgkmcnt cost more than
// any parallel-path gain). Unified model from r9-r18: per-k-iter time =
// 1.2us whenever ~64KB/CU staged/iter => fill pinned at ~22 B/cy/CU; m97
// hit 44 B/cy/CU with 3 INDEPENDENT blocks/CU. Our fused kernel couples all
// 16 waves through a block-wide s_barrier each iter -- every wave stalls
// together. The 4 k-groups are data-independent until the reduction, so:
// replace per-iter s_barrier with a per-group barrier (LDS monotonic
// counter; lane0 fetch_add, all lanes spin on broadcast read + s_sleep).
// Groups drift -> stalls decouple, emulating 4 independent blocks per CU.
// vmcnt(4) before each signal guarantees the wave's own DMA share landed;
// the barrier propagates completion group-wide. sched_barrier(0) pins
// ds_reads below the barrier (rule #18); s_setprio(1) around MFMA (T5 --
// drifted groups give the scheduler a role-split to arbitrate). Final
// __syncthreads() collects drifted groups before the LDS-reuse reduction.
// Everything else r15 verbatim. ws end @ 56,623,104 < 256 MiB.
// ---------------------------------------------------------------------------

#define N_DIM 4096
#define B_DIM 256
#define T_STEPS 32
#define LR_X 0.1f
#define N0 768                      // first live column (aligned down from 784)
#define N_LIVE 3328                 // 4096 - 768 = 52*64
#define NCHL 52                     // live k-chunks (both GEMMs)
#define KG 4                        // k-groups per block
#define KITG 13                     // chunks per group (52/4)

typedef unsigned short ushort_t;
using bf16x8 = __attribute__((ext_vector_type(8))) __bf16;
using f32x4  = __attribute__((ext_vector_type(4))) float;

__device__ __forceinline__ ushort_t f2bf(float f) {
    union { float f; unsigned int u; } v; v.f = f;
    unsigned int r = v.u + 0x7fffu + ((v.u >> 16) & 1u);   // RNE
    return (ushort_t)(r >> 16);
}
__device__ __forceinline__ float bf2f(ushort_t h) {
    union { unsigned int u; float f; } v; v.u = ((unsigned int)h) << 16;
    return v.f;
}

__device__ __forceinline__ void async_copy16(const ushort_t* g, ushort_t* l) {
    __builtin_amdgcn_global_load_lds(
        (__attribute__((address_space(1))) void*)(g),
        (__attribute__((address_space(3))) void*)(l),
        16, 0, 0);
}

// --- pack w -> w_pk [52 ntile][64 chunk][4096]  (B of GEMM1: rows 768..4095)
//            -> wt_pk [52 ntile][52 chunk][4096] (B of GEMM2: w^T, live range)
__global__ __launch_bounds__(256) void pack_w(const float* __restrict__ w,
                                              ushort_t* __restrict__ wpk,
                                              ushort_t* __restrict__ wtpk) {
    __shared__ float tile[64][68];
    const int tid = threadIdx.x;
    const int bid = blockIdx.x;
    int row0, col0; ushort_t* dst; bool tr;
    if (bid < 52 * 64) {
        tr   = false;
        dst  = wpk + (size_t)bid * 4096;
        row0 = N0 + (bid >> 6) * 64;      // B-row (n) block
        col0 = (bid & 63) * 64;           // k block
    } else {
        const int b2 = bid - 52 * 64;
        tr   = true;
        dst  = wtpk + (size_t)b2 * 4096;
        const int ntile = b2 / 52, chunk = b2 - ntile * 52;
        row0 = N0 + chunk * 64;           // w-row  = k block (live)
        col0 = N0 + ntile * 64;           // w-col  = n block (live)
    }
    const int rr = tid >> 2, c0 = (tid & 3) * 16;
    const float* src = w + (size_t)(row0 + rr) * N_DIM + col0 + c0;
#pragma unroll
    for (int i = 0; i < 16; i += 4)
        *(float4*)&tile[rr][c0 + i] = *(const float4*)(src + i);
    __syncthreads();
    ushort_t loc[16];
#pragma unroll
    for (int i = 0; i < 16; ++i) {
        const int p = tid * 16 + i;
        const int s = p >> 9, e = p & 511;
        const int r = ((s >> 1) << 4) | ((e >> 3) & 15);
        const int c = ((s & 1) << 5) | (((e >> 7) & 3) << 3) | (e & 7);
        loc[i] = f2bf(tr ? tile[c][r] : tile[r][c]);
    }
    *(uint4*)&dst[tid * 16]     = *(uint4*)&loc[0];
    *(uint4*)&dst[tid * 16 + 8] = *(uint4*)&loc[8];
}

// --- init: x -> d_out (row-major) and t_pk [4 mtile][64 chunk][4096] --------
__global__ __launch_bounds__(256) void pack_t_init(const float* __restrict__ xin,
                                                   float* __restrict__ xout,
                                                   ushort_t* __restrict__ tpk) {
    __shared__ float tile[64][68];
    const int tid  = threadIdx.x;
    const int bid  = blockIdx.x;          // mtile*64 + chunk
    const int row0 = (bid >> 6) * 64;
    const int col0 = (bid & 63) * 64;
    const int rr = tid >> 2, c0 = (tid & 3) * 16;
    const size_t sidx = (size_t)(row0 + rr) * N_DIM + col0 + c0;
#pragma unroll
    for (int i = 0; i < 16; i += 4) {
        float4 v = *(const float4*)(xin + sidx + i);
        *(float4*)(xout + sidx + i) = v;
        tile[rr][c0 + i + 0] = tanhf(v.x);
        tile[rr][c0 + i + 1] = tanhf(v.y);
        tile[rr][c0 + i + 2] = tanhf(v.z);
        tile[rr][c0 + i + 3] = tanhf(v.w);
    }
    __syncthreads();
    ushort_t loc[16];
    ushort_t* dst = tpk + (size_t)bid * 4096;
#pragma unroll
    for (int i = 0; i < 16; ++i) {
        const int p = tid * 16 + i;
        const int s = p >> 9, e = p & 511;
        const int r = ((s >> 1) << 4) | ((e >> 3) & 15);
        const int c = ((s & 1) << 5) | (((e >> 7) & 3) << 3) | (e & 7);
        loc[i] = f2bf(tile[r][c]);
    }
    *(uint4*)&dst[tid * 16]     = *(uint4*)&loc[0];
    *(uint4*)&dst[tid * 16 + 8] = *(uint4*)&loc[8];
}

// --- one-time: mu0 = tanh(x_sensory) @ w_sensory^T  (k = chunks 0..11) ------
__global__ __launch_bounds__(256) void gemm_mu0(const ushort_t* __restrict__ Apk,
                                                const ushort_t* __restrict__ Bpk,
                                                float* __restrict__ mu0) {
    __shared__ __align__(16) ushort_t As[2][4096];
    __shared__ __align__(16) ushort_t Bs[2][4096];
    const int tid  = threadIdx.x;
    const int lane = tid & 63;
    const int wid  = tid >> 6;
    const int wave_m = wid >> 1, wave_n = wid & 1;
    const int ntile = blockIdx.x, mtile = blockIdx.y;

    const ushort_t* Ab = Apk + (size_t)mtile * 64 * 4096;
    const ushort_t* Bb = Bpk + (size_t)ntile * 64 * 4096;

    auto stage = [&](int buf, int kt) {
#pragma unroll
        for (int u = 0; u < 2; ++u) {
            const int off = (wid * 2 + u) * 512 + lane * 8;
            async_copy16(Ab + (size_t)kt * 4096 + off, &As[buf][off]);
            async_copy16(Bb + (size_t)kt * 4096 + off, &Bs[buf][off]);
        }
    };
    f32x4 acc[2][2] = {};
    auto compute = [&](int buf) {
#pragma unroll
        for (int ks = 0; ks < 2; ++ks) {
            bf16x8 a[2], b[2];
#pragma unroll
            for (int i = 0; i < 2; ++i) {
                const int asub = (wave_m * 2 + i) * 2 + ks;
                const int bsub = (wave_n * 2 + i) * 2 + ks;
                a[i] = *(const bf16x8*)(&As[buf][asub * 512 + lane * 8]);
                b[i] = *(const bf16x8*)(&Bs[buf][bsub * 512 + lane * 8]);
            }
#pragma unroll
            for (int i = 0; i < 2; ++i)
#pragma unroll
                for (int j = 0; j < 2; ++j)
                    acc[i][j] = __builtin_amdgcn_mfma_f32_16x16x32_bf16(
                        a[i], b[j], acc[i][j], 0, 0, 0);
        }
    };
    stage(0, 0);
    __syncthreads();
    for (int kt = 0; kt < 12; ++kt) {          // sensory chunks 0..11
        if (kt + 1 < 12) stage((kt + 1) & 1, kt + 1);
        compute(kt & 1);
        __syncthreads();
    }
    const int l15 = lane & 15, quad = lane >> 4;
#pragma unroll
    for (int j = 0; j < 2; ++j) {
        const int nl = ntile * 64 + wave_n * 32 + j * 16 + l15;
#pragma unroll
        for (int i = 0; i < 2; ++i)
#pragma unroll
            for (int r = 0; r < 4; ++r) {
                const int m = mtile * 64 + wave_m * 32 + i * 16 + quad * 4 + r;
                mu0[(size_t)m * N_LIVE + nl] = acc[i][j][r];
            }
    }
}

// --- fused full-K GEMM + cvt epilogue, per-group barriers -------------------
// Apk: [4 mtile][SA chunk][4096], Bpk: [52 ntile][SB chunk][4096].
// 208 active blocks (52 ntile x 4 mtile), 1024 threads = 4 k-groups x 4
// waves. Group g: chunks CO+g*13..+12, own LDS dbuf, 4-wave compute.
// Per-iter sync is a GROUP-LOCAL LDS-atomic barrier (not s_barrier), so the
// 4 groups drift and their staging stalls decouple (emulates 4 independent
// blocks/CU -- m97's 44 B/cy/CU regime). vmcnt(4) before each signal.
// STAGING RULE: per-lane LDS stride EXACTLY 16B, wave-uniform base.
// Epilogue identical to r15. XCD-pinned ntiles.
template <int SA, int SB, int CO, int PHASE>
__global__ __launch_bounds__(1024) void gemm_fused(
    const ushort_t* __restrict__ Apk,
    const ushort_t* __restrict__ Bpk,
    float* __restrict__ xbuf,
    const float* __restrict__ mu0,
    const int* __restrict__ mask,
    ushort_t* __restrict__ epk,
    ushort_t* __restrict__ tpk) {
    __shared__ __align__(16) ushort_t smem[65536];   // 128 KB
    __shared__ unsigned gbar[KG];                    // group barrier counters
    ushort_t* As = smem;                              // [g*2+buf][4096]
    ushort_t* Bs = smem + 32768;                      // [g*2+buf][4096]

    const int bid = blockIdx.x;
    const int xcd = bid & 7;
    const int i   = bid >> 3;                 // 0..31
    const int nloc = (xcd < 4) ? 7 : 6;
    if (i >= nloc * 4) return;
    const int n0    = (xcd < 4) ? xcd * 7 : 28 + (xcd - 4) * 6;
    const int ntile = n0 + (i >> 2);          // 0..51
    const int mtile = i & 3;                  // 0..3

    const int tid  = threadIdx.x;
    const int lane = tid & 63;
    const int g    = tid >> 8;                // k-group 0..3
    const int gtid = tid & 255;
    const int gw   = (tid >> 6) & 3;          // wave within group
    const int wave_m = gw >> 1, wave_n = gw & 1;

    if (tid < KG) gbar[tid] = 0u;
    __syncthreads();

    const ushort_t* Ab = Apk + ((size_t)mtile * SA + CO + g * KITG) * 4096;
    const ushort_t* Bb = Bpk + ((size_t)ntile * SB + CO + g * KITG) * 4096;

    ushort_t* Asg = As + g * 2 * 4096;
    ushort_t* Bsg = Bs + g * 2 * 4096;

    auto stage = [&](int buf, int kt) {
        const ushort_t* Ac = Ab + (size_t)kt * 4096;
        const ushort_t* Bc = Bb + (size_t)kt * 4096;
#pragma unroll
        for (int u = 0; u < 2; ++u) {
            // lane stride 16B, wave-uniform base (u*4096 + gw*1024 bytes)
            const int off = (u * 256 + gtid) * 8;
            async_copy16(Ac + off, &Asg[buf * 4096 + off]);
            async_copy16(Bc + off, &Bsg[buf * 4096 + off]);
        }
    };

    // group-local barrier: monotonic LDS counter, 4 waves per group
    unsigned xing = 0;
    auto group_bar = [&]() {
        xing += 4;
        if (lane == 0)
            __hip_atomic_fetch_add(&gbar[g], 1u, __ATOMIC_RELAXED,
                                   __HIP_MEMORY_SCOPE_WORKGROUP);
        while (__hip_atomic_load(&gbar[g], __ATOMIC_RELAXED,
                                 __HIP_MEMORY_SCOPE_WORKGROUP) < xing)
            __builtin_amdgcn_s_sleep(1);
    };

    f32x4 acc[2][2] = {};

    auto compute = [&](int buf) {
        __builtin_amdgcn_s_setprio(1);
#pragma unroll
        for (int ks = 0; ks < 2; ++ks) {
            bf16x8 a[2], b[2];
#pragma unroll
            for (int i2 = 0; i2 < 2; ++i2) {
                const int asub = (wave_m * 2 + i2) * 2 + ks;
                const int bsub = (wave_n * 2 + i2) * 2 + ks;
                a[i2] = *(const bf16x8*)(&Asg[buf * 4096 + asub * 512 + lane * 8]);
                b[i2] = *(const bf16x8*)(&Bsg[buf * 4096 + bsub * 512 + lane * 8]);
            }
#pragma unroll
            for (int i2 = 0; i2 < 2; ++i2)
#pragma unroll
                for (int j = 0; j < 2; ++j)
                    acc[i2][j] = __builtin_amdgcn_mfma_f32_16x16x32_bf16(
                        a[i2], b[j], acc[i2][j], 0, 0, 0);
        }
        __builtin_amdgcn_s_setprio(0);
    };

    // ---- k-loop: counted vmcnt + per-group barriers (groups drift) ---------
    stage(0, 0);
    for (int kt = 0; kt < KITG; ++kt) {
        if (kt + 1 < KITG) {
            stage((kt + 1) & 1, kt + 1);
            asm volatile("s_waitcnt vmcnt(4)" ::: "memory");
        } else {
            asm volatile("s_waitcnt vmcnt(0)" ::: "memory");
        }
        group_bar();                          // tile kt landed group-wide
        __builtin_amdgcn_sched_barrier(0);
        compute(kt & 1);
        group_bar();                          // buf kt&1 fully consumed
    }
    __syncthreads();                     // collect drifted groups; reuse LDS

    // ---- cross-group f32 reduction: red[g] = 64x68-padded f32 tile ---------
    float* red = (float*)smem;           // 4 x 64*68*4B = 69.6 KB
    const int RP = 64 * 68;
    {
        const int l15 = lane & 15, quad = lane >> 4;
#pragma unroll
        for (int j = 0; j < 2; ++j) {
            const int col = wave_n * 32 + j * 16 + l15;
#pragma unroll
            for (int i2 = 0; i2 < 2; ++i2)
#pragma unroll
                for (int r = 0; r < 4; ++r) {
                    const int row = wave_m * 32 + i2 * 16 + quad * 4 + r;
                    red[g * RP + row * 68 + col] = acc[i2][j][r];
                }
        }
    }
    __syncthreads();

    // ---- fused epilogue: thread owns 4 consecutive packed positions --------
    const int p4 = tid * 4;
    const int s  = p4 >> 9, e9 = p4 & 511;
    const int r  = ((s >> 1) << 4) | ((e9 >> 3) & 15);
    const int c  = ((s & 1) << 5) | (((e9 >> 7) & 3) << 3) | (e9 & 7);

    float4 sv = *(const float4*)&red[0 * RP + r * 68 + c];
#pragma unroll
    for (int gg = 1; gg < KG; ++gg) {
        float4 v = *(const float4*)&red[gg * RP + r * 68 + c];
        sv.x += v.x; sv.y += v.y; sv.z += v.z; sv.w += v.w;
    }

    const int grow = mtile * 64 + r;          // batch row
    const int gcl  = ntile * 64 + c;          // live col
    const size_t xi = (size_t)grow * N_DIM + N0 + gcl;
    float4 xv = *(const float4*)&xbuf[xi];
    int4   mk = *(const int4*)&mask[N0 + gcl];

    if (PHASE == 1) {
        float4 m0 = *(const float4*)&mu0[(size_t)grow * N_LIVE + gcl];
        ushort_t ev[4];
        ev[0] = f2bf((xv.x - (m0.x + sv.x)) * (float)mk.x);
        ev[1] = f2bf((xv.y - (m0.y + sv.y)) * (float)mk.y);
        ev[2] = f2bf((xv.z - (m0.z + sv.z)) * (float)mk.z);
        ev[3] = f2bf((xv.w - (m0.w + sv.w)) * (float)mk.w);
        *(uint2*)&epk[((size_t)(mtile * NCHL + ntile)) * 4096 + p4]
            = *(uint2*)&ev[0];
    } else {
        // e read back through Apk (Apk IS e_pk in phase 2; same packed chunk)
        const ushort_t* ech = Apk + ((size_t)(mtile * SA + ntile)) * 4096;
        ushort_t ein[4];
        *(uint2*)&ein[0] = *(const uint2*)&ech[p4];
        float xn[4]; ushort_t tv[4];
        const float* svp = &sv.x;
        const int*   mkp = &mk.x;
        const float* xvp = &xv.x;
#pragma unroll
        for (int q = 0; q < 4; ++q) {
            const float x  = xvp[q];
            const float th = tanhf(x);
            const float ee = bf2f(ein[q]);
            xn[q] = x - LR_X * (float)mkp[q] * (ee - (1.0f - th * th) * svp[q]);
            tv[q] = f2bf(tanhf(xn[q]));
        }
        *(float4*)&xbuf[xi] = make_float4(xn[0], xn[1], xn[2], xn[3]);
        *(uint2*)&tpk[((size_t)(mtile * 64 + 12 + ntile)) * 4096 + p4]
            = *(uint2*)&tv[0];
    }
}

extern "C" void kernel_launch(void* const* d_in, const int* in_sizes, int n_in,
                              void* d_out, int out_size, void* d_ws, size_t ws_size,
                              hipStream_t stream) {
    const float* x_in  = (const float*)d_in[0];
    const float* w_in  = (const float*)d_in[1];
    const int*   mask  = (const int*)d_in[2];
    float*       xbuf  = (float*)d_out;          // state lives in d_out

    uint8_t* ws = (uint8_t*)d_ws;
    // ws layout (end @ 56,623,104 bytes; ws_size = 256 MiB per fillBuffer):
    ushort_t* w_pk  = (ushort_t*)(ws);                   // 52*64*4096*2 = 27,262,976
    ushort_t* wt_pk = (ushort_t*)(ws + 27262976);        // 52*52*4096*2 = 22,151,168
    ushort_t* t_pk  = (ushort_t*)(ws + 49414144);        //  4*64*4096*2 =  2,097,152
    ushort_t* e_pk  = (ushort_t*)(ws + 51511296);        //  4*52*4096*2 =  1,703,936
    float*    mu0   = (float*)(ws + 53215232);           //  256*3328*4  =  3,407,872

    pack_w<<<dim3(52 * 64 + 52 * 52), 256, 0, stream>>>(w_in, w_pk, wt_pk);
    pack_t_init<<<dim3(4 * 64), 256, 0, stream>>>(x_in, xbuf, t_pk);
    gemm_mu0<<<dim3(52, 4), 256, 0, stream>>>(t_pk, w_pk, mu0);

    for (int t = 0; t < T_STEPS; ++t) {
        // GEMM1+cvt1: e = (x - mu)*mask -> e_pk   (A = t_pk, B = w_pk)
        gemm_fused<64, 64, 12, 1><<<256, 1024, 0, stream>>>(
            t_pk, w_pk, xbuf, mu0, mask, e_pk, t_pk);
        // GEMM2+cvt2: x update -> xbuf, tanh -> t_pk (A = e_pk, B = wt_pk)
        gemm_fused<52, 52, 0, 2><<<256, 1024, 0, stream>>>(
            e_pk, wt_pk, xbuf, mu0, mask, e_pk, t_pk);
    }
}